// Round 1
// baseline (356.771 us; speedup 1.0000x reference)
//
#include <hip/hip_runtime.h>
#include <hip/hip_bf16.h>
#include <stdint.h>

#define BATCH  512
#define INPUT  20000
#define HIDDEN 1024
#define EMBED  512
#define NOUT   2048

#define BM 128
#define BN 128
#define BK 64
#define LDSS 72   // LDS row stride in bf16 elements (BK + 8 pad)

typedef __attribute__((ext_vector_type(8))) __bf16 bf16x8;
typedef __attribute__((ext_vector_type(8))) unsigned short u16x8;
typedef __attribute__((ext_vector_type(4))) unsigned short u16x4;
typedef __attribute__((ext_vector_type(4))) float f32x4;

static __device__ __forceinline__ unsigned short f2bf(float f) {
  uint32_t u = __builtin_bit_cast(uint32_t, f);
  u += 0x7fffu + ((u >> 16) & 1u);          // round-to-nearest-even
  return (unsigned short)(u >> 16);
}

// Stage a BMxBK (or BNxBK) tile from global (f32 or bf16) into LDS as bf16.
// TYP: 0 = f32 source (convert), 1 = bf16 source. Zero-fills out-of-bounds.
template<int TYP>
static __device__ __forceinline__ void stage_tile(
    const void* __restrict__ src, int ld, int rbound, int r0, int kb, int K,
    unsigned short* __restrict__ dst, int tid)
{
#pragma unroll
  for (int i = 0; i < 4; ++i) {
    int c   = i * 256 + tid;       // 1024 chunks of 8 elems = 128x64
    int row = c >> 3;
    int kk  = (c & 7) << 3;
    int gk  = kb + kk;
    u16x8 v = {};
    if (gk < K && (r0 + row) < rbound) {   // K % 8 == 0 for all our GEMMs
      if (TYP == 1) {
        v = *reinterpret_cast<const u16x8*>(
              reinterpret_cast<const unsigned short*>(src) + (size_t)(r0 + row) * ld + gk);
      } else {
        const float* p = reinterpret_cast<const float*>(src) + (size_t)(r0 + row) * ld + gk;
        f32x4 f0 = *reinterpret_cast<const f32x4*>(p);
        f32x4 f1 = *reinterpret_cast<const f32x4*>(p + 4);
        v[0] = f2bf(f0[0]); v[1] = f2bf(f0[1]); v[2] = f2bf(f0[2]); v[3] = f2bf(f0[3]);
        v[4] = f2bf(f1[0]); v[5] = f2bf(f1[1]); v[6] = f2bf(f1[2]); v[7] = f2bf(f1[3]);
      }
    }
    *reinterpret_cast<u16x8*>(dst + row * LDSS + kk) = v;
  }
}

// C = A @ B^T, A:[M,K] (lda), B:[N,K] (ldb), both K-contiguous.
// AT/BT_: element type of A/B (0=f32, 1=bf16).
// EPI 0: C[m,n] = bf16(lrelu(acc + bias[m])), ldc row stride (Et GEMM).
// EPI 1: raw f32 partials at Cp + z*M*ldc + m*ldc + n (split-K).
template<int AT, int BT_, int EPI>
__global__ __launch_bounds__(256) void gemm_bt(
    const void* __restrict__ Ap, int lda,
    const void* __restrict__ Bp, int ldb,
    const float* __restrict__ bias,
    void* __restrict__ Cp, int ldc,
    int M, int N, int K, int kChunk)
{
  __shared__ __align__(16) unsigned short As[BM * LDSS];
  __shared__ __align__(16) unsigned short Bs[BN * LDSS];

  const int nt = blockIdx.x, mt = blockIdx.y, z = blockIdx.z;
  const int m0 = mt * BM, n0 = nt * BN;
  const int k0   = z * kChunk;
  const int kend = min(K, k0 + kChunk);
  const int tid = threadIdx.x;
  const int l  = tid & 63;
  const int w  = tid >> 6;
  const int wm = (w >> 1) * 64;
  const int wn = (w & 1) * 64;
  const int lr = l & 15;           // A-row / B-col / C-col lane index
  const int lk = (l >> 4) * 8;     // k sub-offset within fragment

  f32x4 acc[4][4] = {};

  for (int kb = k0; kb < kend; kb += BK) {
    stage_tile<AT >(Ap, lda, M, m0, kb, K, As, tid);
    stage_tile<BT_>(Bp, ldb, N, n0, kb, K, Bs, tid);
    __syncthreads();
#pragma unroll
    for (int ks = 0; ks < 2; ++ks) {
      bf16x8 a[4], b[4];
#pragma unroll
      for (int i = 0; i < 4; ++i)
        a[i] = *reinterpret_cast<const bf16x8*>(&As[(wm + i * 16 + lr) * LDSS + ks * 32 + lk]);
#pragma unroll
      for (int i = 0; i < 4; ++i)
        b[i] = *reinterpret_cast<const bf16x8*>(&Bs[(wn + i * 16 + lr) * LDSS + ks * 32 + lk]);
#pragma unroll
      for (int mi = 0; mi < 4; ++mi)
#pragma unroll
        for (int ni = 0; ni < 4; ++ni)
          acc[mi][ni] = __builtin_amdgcn_mfma_f32_16x16x32_bf16(a[mi], b[ni], acc[mi][ni], 0, 0, 0);
    }
    __syncthreads();
  }

  // C/D layout: col = lane&15, row = (lane>>4)*4 + reg  [measured m89/m91]
  const int rb = (l >> 4) * 4;
#pragma unroll
  for (int mi = 0; mi < 4; ++mi) {
#pragma unroll
    for (int ni = 0; ni < 4; ++ni) {
#pragma unroll
      for (int j = 0; j < 4; ++j) {
        int m = m0 + wm + mi * 16 + rb + j;
        int n = n0 + wn + ni * 16 + lr;
        if (m < M && n < N) {
          float v = acc[mi][ni][j];
          if (EPI == 0) {
            v += bias[m];
            v = v > 0.f ? v : 0.01f * v;
            reinterpret_cast<unsigned short*>(Cp)[(size_t)m * ldc + n] = f2bf(v);
          } else {
            reinterpret_cast<float*>(Cp)[(size_t)z * M * ldc + (size_t)m * ldc + n] = v;
          }
        }
      }
    }
  }
}

// Per-row online softmax stats + bf16 casts: xb = bf16(x), wb = bf16(softmax(x)).
__global__ __launch_bounds__(256) void prep_x_kernel(
    const float* __restrict__ x,
    unsigned short* __restrict__ xb,
    unsigned short* __restrict__ wb)
{
  const int r = blockIdx.x;
  const int t = threadIdx.x;
  const float* xr = x + (size_t)r * INPUT;

  float m = -3.4e38f, s = 0.f;
  for (int c = t; c < INPUT / 4; c += 256) {
    float4 v = reinterpret_cast<const float4*>(xr)[c];
    float cm = fmaxf(fmaxf(v.x, v.y), fmaxf(v.z, v.w));
    if (cm > m) { s *= __expf(m - cm); m = cm; }
    s += __expf(v.x - m) + __expf(v.y - m) + __expf(v.z - m) + __expf(v.w - m);
  }
#pragma unroll
  for (int off = 32; off > 0; off >>= 1) {
    float om = __shfl_xor(m, off);
    float os = __shfl_xor(s, off);
    float nm = fmaxf(m, om);
    s = s * __expf(m - nm) + os * __expf(om - nm);
    m = nm;
  }
  __shared__ float sm[4], ss[4];
  if ((t & 63) == 0) { sm[t >> 6] = m; ss[t >> 6] = s; }
  __syncthreads();
  float M4 = fmaxf(fmaxf(sm[0], sm[1]), fmaxf(sm[2], sm[3]));
  float S4 = ss[0] * __expf(sm[0] - M4) + ss[1] * __expf(sm[1] - M4)
           + ss[2] * __expf(sm[2] - M4) + ss[3] * __expf(sm[3] - M4);
  float inv = 1.f / S4;

  unsigned short* xbr = xb + (size_t)r * INPUT;
  unsigned short* wbr = wb + (size_t)r * INPUT;
  for (int c = t; c < INPUT / 4; c += 256) {
    float4 v = reinterpret_cast<const float4*>(xr)[c];
    u16x4 xo, wo;
    xo[0] = f2bf(v.x); xo[1] = f2bf(v.y); xo[2] = f2bf(v.z); xo[3] = f2bf(v.w);
    wo[0] = f2bf(__expf(v.x - M4) * inv);
    wo[1] = f2bf(__expf(v.y - M4) * inv);
    wo[2] = f2bf(__expf(v.z - M4) * inv);
    wo[3] = f2bf(__expf(v.w - M4) * inv);
    reinterpret_cast<u16x4*>(xbr)[c] = xo;
    reinterpret_cast<u16x4*>(wbr)[c] = wo;
  }
}

// Sum S split-K planes; MODE 0: combined buffer (b_ge+lrelu on cols<1024 only, bf16 out)
//                       MODE 1: final output (b_c+lrelu on all cols, f32 out)
template<int S, int MODE>
__global__ __launch_bounds__(256) void reduce_kernel(
    const float* __restrict__ P, const float* __restrict__ bias, void* __restrict__ outp)
{
  size_t base = ((size_t)blockIdx.x * 256 + threadIdx.x) * 4;
  f32x4 s = {};
#pragma unroll
  for (int zz = 0; zz < S; ++zz)
    s += *reinterpret_cast<const f32x4*>(P + (size_t)zz * BATCH * NOUT + base);
  int n = (int)(base & (NOUT - 1));
  if (MODE == 0) {
    u16x4 o;
    if (n < 1024) {
#pragma unroll
      for (int j = 0; j < 4; ++j) {
        float v = s[j] + bias[n + j];
        v = v > 0.f ? v : 0.01f * v;
        o[j] = f2bf(v);
      }
    } else {
#pragma unroll
      for (int j = 0; j < 4; ++j) o[j] = f2bf(s[j]);
    }
    *reinterpret_cast<u16x4*>(reinterpret_cast<unsigned short*>(outp) + base) = o;
  } else {
    f32x4 o;
#pragma unroll
    for (int j = 0; j < 4; ++j) {
      float v = s[j] + bias[n + j];
      o[j] = v > 0.f ? v : 0.01f * v;
    }
    *reinterpret_cast<f32x4*>(reinterpret_cast<float*>(outp) + base) = o;
  }
}

extern "C" void kernel_launch(void* const* d_in, const int* in_sizes, int n_in,
                              void* d_out, int out_size, void* d_ws, size_t ws_size,
                              hipStream_t stream)
{
  const float* x    = (const float*)d_in[0];
  const float* emb  = (const float*)d_in[1];
  const float* W_ge = (const float*)d_in[2];
  const float* b_ge = (const float*)d_in[3];
  const float* W_em = (const float*)d_in[4];
  const float* b_em = (const float*)d_in[5];
  const float* W_c  = (const float*)d_in[6];
  const float* b_c  = (const float*)d_in[7];
  float* out = (float*)d_out;

  char* ws = (char*)d_ws;
  unsigned short* xb   = (unsigned short*)(ws);                       // 512x20000 bf16 = 20.48 MB
  unsigned short* wb   = (unsigned short*)(ws + 20480000);            // 20.48 MB
  unsigned short* Et   = (unsigned short*)(ws + 40960000);            // 1024x20000 bf16 = 40.96 MB
  float*          P    = (float*)(ws + 81920000);                     // 16x512x2048 f32 = 67.1 MB
  unsigned short* comb = (unsigned short*)(ws + 81920000 + (size_t)16 * BATCH * NOUT * 4); // 2.1 MB

  // 1) softmax stats + bf16 casts of x
  prep_x_kernel<<<BATCH, 256, 0, stream>>>(x, xb, wb);

  // 2) Et[h,g] = lrelu(W_em @ emb^T + b_em): M=1024, N=20000, K=512
  gemm_bt<0, 0, 0><<<dim3(157, 8, 1), 256, 0, stream>>>(
      W_em, EMBED, emb, EMBED, b_em, Et, INPUT, HIDDEN, INPUT, EMBED, EMBED);

  // 3) partials cols 0..1023: xb @ W_ge^T  (M=512, N=1024, K=20000, S=16)
  gemm_bt<1, 0, 1><<<dim3(8, 4, 16), 256, 0, stream>>>(
      xb, INPUT, W_ge, INPUT, nullptr, P, NOUT, BATCH, HIDDEN, INPUT, 1280);

  // 4) partials cols 1024..2047: wb @ Et^T
  gemm_bt<1, 1, 1><<<dim3(8, 4, 16), 256, 0, stream>>>(
      wb, INPUT, Et, INPUT, nullptr, P + 1024, NOUT, BATCH, HIDDEN, INPUT, 1280);

  // 5) reduce 16 planes -> combined bf16 [512, 2048]
  reduce_kernel<16, 0><<<(BATCH * NOUT / 4) / 256, 256, 0, stream>>>(P, b_ge, comb);

  // 6) partials: combined @ W_c^T (M=512, N=2048, K=2048, S=4)
  gemm_bt<1, 0, 1><<<dim3(16, 4, 4), 256, 0, stream>>>(
      comb, NOUT, W_c, NOUT, nullptr, P, NOUT, BATCH, NOUT, NOUT, 512);

  // 7) reduce 4 planes + b_c + lrelu -> f32 out [512, 2048]
  reduce_kernel<4, 1><<<(BATCH * NOUT / 4) / 256, 256, 0, stream>>>(P, b_c, out);
}

// Round 2
// 256.359 us; speedup vs baseline: 1.3917x; 1.3917x over previous
//
#include <hip/hip_runtime.h>
#include <hip/hip_bf16.h>
#include <stdint.h>

#define BATCH  512
#define INPUT  20000
#define KPAD   20032     // INPUT padded to multiple of 64 (zero-filled tail)
#define NPADE  20096     // emb rows padded to multiple of 128 (zero-filled)
#define HIDDEN 1024
#define EMBED  512
#define NOUT   2048

typedef __attribute__((ext_vector_type(8))) __bf16 bf16x8;
typedef __attribute__((ext_vector_type(8))) unsigned short u16x8;
typedef __attribute__((ext_vector_type(4))) unsigned short u16x4;
typedef __attribute__((ext_vector_type(4))) float f32x4;

static __device__ __forceinline__ unsigned short f2bf(float f) {
  uint32_t u = __builtin_bit_cast(uint32_t, f);
  u += 0x7fffu + ((u >> 16) & 1u);          // round-to-nearest-even
  return (unsigned short)(u >> 16);
}

// async global->LDS, 16 bytes/lane; LDS dest must be wave-uniform base (+lane*16 in HW)
static __device__ __forceinline__ void g2l16(const unsigned short* g, unsigned short* l) {
  __builtin_amdgcn_global_load_lds(
      (const __attribute__((address_space(1))) void*)g,
      (__attribute__((address_space(3))) void*)l, 16, 0, 0);
}

// f32 [rows,cols] -> bf16 [rowsPad,colsPad], zero-filled padding. cols % 8 == 0.
__global__ __launch_bounds__(256) void convert_kernel(
    const float* __restrict__ src, unsigned short* __restrict__ dst,
    int rows, int cols, int rowsPad, int colsPad)
{
  const int cpc = colsPad >> 3;             // chunks per row
  const int nchunks = rowsPad * cpc;
  for (int idx = blockIdx.x * 256 + threadIdx.x; idx < nchunks; idx += gridDim.x * 256) {
    int row = idx / cpc;
    int c0  = (idx - row * cpc) << 3;
    u16x8 v = {};
    if (row < rows && c0 < cols) {
      const float* p = src + (size_t)row * cols + c0;
      f32x4 f0 = *reinterpret_cast<const f32x4*>(p);
      f32x4 f1 = *reinterpret_cast<const f32x4*>(p + 4);
      v[0] = f2bf(f0[0]); v[1] = f2bf(f0[1]); v[2] = f2bf(f0[2]); v[3] = f2bf(f0[3]);
      v[4] = f2bf(f1[0]); v[5] = f2bf(f1[1]); v[6] = f2bf(f1[2]); v[7] = f2bf(f1[3]);
    }
    *reinterpret_cast<u16x8*>(dst + (size_t)row * colsPad + c0) = v;
  }
}

// C = A @ B^T with bf16 operands (K-contiguous), m97 structure:
// 128x128 tile, BK=64, 4 waves (2x2 of 64x64), global_load_lds 16B staging, linear LDS.
// EPI 0: C[m,n] = bf16(lrelu(acc+bias[m])) for n<N, 0 for N<=n<Nw (zero-pad cols).
// EPI 1: f32 split-K planes: Cp + z*pstride + m*ldc + which*1024 + n.
// FUSED: blockIdx.z>>ZBITS selects operand set {A0,B0} vs {A1,B1} and +1024 col offset.
template<int EPI, int FUSED, int ZBITS>
__global__ __launch_bounds__(256) void gemm97(
    const unsigned short* __restrict__ A0, const unsigned short* __restrict__ B0,
    const unsigned short* __restrict__ A1, const unsigned short* __restrict__ B1,
    int lda, int ldb,
    const float* __restrict__ bias,
    void* __restrict__ Cp, int ldc, int pstride,
    int M, int N, int Nw, int K, int kChunk)
{
  __shared__ __align__(16) unsigned short As[128 * 64];
  __shared__ __align__(16) unsigned short Bs[128 * 64];

  const int zall  = blockIdx.z;
  const int which = FUSED ? (zall >> ZBITS) : 0;
  const int z     = FUSED ? (zall & ((1 << ZBITS) - 1)) : zall;
  const unsigned short* A = (FUSED && which) ? A1 : A0;
  const unsigned short* B = (FUSED && which) ? B1 : B0;

  const int m0 = blockIdx.y * 128, n0 = blockIdx.x * 128;
  const int k0   = z * kChunk;
  const int kend = min(K, k0 + kChunk);
  const int tid = threadIdx.x;
  const int l = tid & 63, w = tid >> 6;

  // staging addresses: wave w stages rows [w*32, w*32+32) of each tile,
  // 4 issues of 8 rows; lane l -> row +(l>>3), cols (l&7)*8 .. +8
  const int srow = w * 32 + (l >> 3);
  const int scol = (l & 7) * 8;
  const unsigned short* ag = A + (size_t)(m0 + srow) * lda + scol;
  const unsigned short* bg = B + (size_t)(n0 + srow) * ldb + scol;

  const int wm = (w >> 1) * 64, wn = (w & 1) * 64;
  const int lr = l & 15, lk = (l >> 4) * 8;

  f32x4 acc[4][4] = {};

  for (int kb = k0; kb < kend; kb += 64) {
#pragma unroll
    for (int j = 0; j < 4; ++j)
      g2l16(ag + (size_t)j * 8 * lda + kb, As + (w * 32 + j * 8) * 64);
#pragma unroll
    for (int j = 0; j < 4; ++j)
      g2l16(bg + (size_t)j * 8 * ldb + kb, Bs + (w * 32 + j * 8) * 64);
    __syncthreads();
#pragma unroll
    for (int ks = 0; ks < 2; ++ks) {
      bf16x8 a[4], b[4];
#pragma unroll
      for (int i = 0; i < 4; ++i)
        a[i] = *reinterpret_cast<const bf16x8*>(&As[(wm + i * 16 + lr) * 64 + ks * 32 + lk]);
#pragma unroll
      for (int i = 0; i < 4; ++i)
        b[i] = *reinterpret_cast<const bf16x8*>(&Bs[(wn + i * 16 + lr) * 64 + ks * 32 + lk]);
#pragma unroll
      for (int mi = 0; mi < 4; ++mi)
#pragma unroll
        for (int ni = 0; ni < 4; ++ni)
          acc[mi][ni] = __builtin_amdgcn_mfma_f32_16x16x32_bf16(a[mi], b[ni], acc[mi][ni], 0, 0, 0);
    }
    __syncthreads();
  }

  // C/D layout: col = lane&15, row = (lane>>4)*4 + reg  [m89/m91]
  const int rb = (l >> 4) * 4;
#pragma unroll
  for (int mi = 0; mi < 4; ++mi) {
#pragma unroll
    for (int ni = 0; ni < 4; ++ni) {
#pragma unroll
      for (int j = 0; j < 4; ++j) {
        int m = m0 + wm + mi * 16 + rb + j;
        int n = n0 + wn + ni * 16 + lr;
        float v = acc[mi][ni][j];
        if (EPI == 0) {
          if (n < Nw) {
            float t = v + bias[m];
            t = t > 0.f ? t : 0.01f * t;
            reinterpret_cast<unsigned short*>(Cp)[(size_t)m * ldc + n] =
                (n < N) ? f2bf(t) : (unsigned short)0;
          }
        } else {
          reinterpret_cast<float*>(Cp)[(size_t)z * pstride + (size_t)m * ldc +
                                       (FUSED ? which * 1024 : 0) + n] = v;
        }
      }
    }
  }
}

// Per-row softmax stats + bf16 casts: xb = bf16(x), wb = bf16(softmax(x)),
// written at stride KPAD with zero-filled tail cols.
__global__ __launch_bounds__(256) void prep_x_kernel(
    const float* __restrict__ x,
    unsigned short* __restrict__ xb,
    unsigned short* __restrict__ wb)
{
  const int r = blockIdx.x;
  const int t = threadIdx.x;
  const float* xr = x + (size_t)r * INPUT;

  float m = -3.4e38f, s = 0.f;
  for (int c = t; c < INPUT / 4; c += 256) {
    float4 v = reinterpret_cast<const float4*>(xr)[c];
    float cm = fmaxf(fmaxf(v.x, v.y), fmaxf(v.z, v.w));
    if (cm > m) { s *= __expf(m - cm); m = cm; }
    s += __expf(v.x - m) + __expf(v.y - m) + __expf(v.z - m) + __expf(v.w - m);
  }
#pragma unroll
  for (int off = 32; off > 0; off >>= 1) {
    float om = __shfl_xor(m, off);
    float os = __shfl_xor(s, off);
    float nm = fmaxf(m, om);
    s = s * __expf(m - nm) + os * __expf(om - nm);
    m = nm;
  }
  __shared__ float sm[4], ss[4];
  if ((t & 63) == 0) { sm[t >> 6] = m; ss[t >> 6] = s; }
  __syncthreads();
  float M4 = fmaxf(fmaxf(sm[0], sm[1]), fmaxf(sm[2], sm[3]));
  float S4 = ss[0] * __expf(sm[0] - M4) + ss[1] * __expf(sm[1] - M4)
           + ss[2] * __expf(sm[2] - M4) + ss[3] * __expf(sm[3] - M4);
  float inv = 1.f / S4;

  unsigned short* xbr = xb + (size_t)r * KPAD;
  unsigned short* wbr = wb + (size_t)r * KPAD;
  for (int c = t; c < KPAD / 4; c += 256) {
    u16x4 xo = {}, wo = {};
    if (c < INPUT / 4) {
      float4 v = reinterpret_cast<const float4*>(xr)[c];
      xo[0] = f2bf(v.x); xo[1] = f2bf(v.y); xo[2] = f2bf(v.z); xo[3] = f2bf(v.w);
      wo[0] = f2bf(__expf(v.x - M4) * inv);
      wo[1] = f2bf(__expf(v.y - M4) * inv);
      wo[2] = f2bf(__expf(v.z - M4) * inv);
      wo[3] = f2bf(__expf(v.w - M4) * inv);
    }
    reinterpret_cast<u16x4*>(xbr)[c] = xo;
    reinterpret_cast<u16x4*>(wbr)[c] = wo;
  }
}

// Sum S split-K planes; MODE 0: combined buffer (b_ge+lrelu on cols<1024 only, bf16 out)
//                       MODE 1: final output (b_c+lrelu on all cols, f32 out)
template<int S, int MODE>
__global__ __launch_bounds__(256) void reduce_kernel(
    const float* __restrict__ P, const float* __restrict__ bias, void* __restrict__ outp)
{
  size_t base = ((size_t)blockIdx.x * 256 + threadIdx.x) * 4;
  f32x4 s = {};
#pragma unroll
  for (int zz = 0; zz < S; ++zz)
    s += *reinterpret_cast<const f32x4*>(P + (size_t)zz * BATCH * NOUT + base);
  int n = (int)(base & (NOUT - 1));
  if (MODE == 0) {
    u16x4 o;
    if (n < 1024) {
#pragma unroll
      for (int j = 0; j < 4; ++j) {
        float v = s[j] + bias[n + j];
        v = v > 0.f ? v : 0.01f * v;
        o[j] = f2bf(v);
      }
    } else {
#pragma unroll
      for (int j = 0; j < 4; ++j) o[j] = f2bf(s[j]);
    }
    *reinterpret_cast<u16x4*>(reinterpret_cast<unsigned short*>(outp) + base) = o;
  } else {
    f32x4 o;
#pragma unroll
    for (int j = 0; j < 4; ++j) {
      float v = s[j] + bias[n + j];
      o[j] = v > 0.f ? v : 0.01f * v;
    }
    *reinterpret_cast<f32x4*>(reinterpret_cast<float*>(outp) + base) = o;
  }
}

extern "C" void kernel_launch(void* const* d_in, const int* in_sizes, int n_in,
                              void* d_out, int out_size, void* d_ws, size_t ws_size,
                              hipStream_t stream)
{
  const float* x    = (const float*)d_in[0];
  const float* emb  = (const float*)d_in[1];
  const float* W_ge = (const float*)d_in[2];
  const float* b_ge = (const float*)d_in[3];
  const float* W_em = (const float*)d_in[4];
  const float* b_em = (const float*)d_in[5];
  const float* W_c  = (const float*)d_in[6];
  const float* b_c  = (const float*)d_in[7];
  float* out = (float*)d_out;

  char* ws = (char*)d_ws;
  // layout (bytes):
  unsigned short* xb   = (unsigned short*)(ws);                      // 512x20032 bf16  = 20,512,768
  unsigned short* wb   = (unsigned short*)(ws + 20512768);           // 20,512,768
  unsigned short* Wgeb = (unsigned short*)(ws + 41025536);           // 1024x20032 bf16 = 41,025,536
  unsigned short* Et   = (unsigned short*)(ws + 82051072);           // 1024x20032 bf16 = 41,025,536
  unsigned short* Wcb  = (unsigned short*)(ws + 123076608);          // 2048x2048 bf16  =  8,388,608
  unsigned short* comb = (unsigned short*)(ws + 131465216);          // 512x2048 bf16   =  2,097,152
  float*          P    = (float*)(ws + 133562368);                   // 16x512x2048 f32 = 67,108,864
  // embb/Wemb alias the P region (dead before P is first written)
  unsigned short* embb = (unsigned short*)(ws + 133562368);          // 20096x512 bf16  = 20,578,304
  unsigned short* Wemb = (unsigned short*)(ws + 133562368 + 20578304); // 1024x512 bf16 =  1,048,576
  // total ws usage: 200,671,232 bytes

  // 1) bf16 conversions (zero-padded)
  convert_kernel<<<1024, 256, 0, stream>>>(emb,  embb, INPUT, EMBED, NPADE, EMBED);
  convert_kernel<<<256,  256, 0, stream>>>(W_em, Wemb, HIDDEN, EMBED, HIDDEN, EMBED);
  convert_kernel<<<1024, 256, 0, stream>>>(W_ge, Wgeb, HIDDEN, INPUT, HIDDEN, KPAD);
  convert_kernel<<<512,  256, 0, stream>>>(W_c,  Wcb,  NOUT, NOUT, NOUT, NOUT);

  // 2) softmax stats + bf16 casts of x (stride KPAD, zero tail)
  prep_x_kernel<<<BATCH, 256, 0, stream>>>(x, xb, wb);

  // 3) Et[h,g] = lrelu(W_em @ emb^T + b_em): M=1024, N=20000 (Nw=20032), K=512
  gemm97<0, 0, 0><<<dim3(157, 8, 1), 256, 0, stream>>>(
      Wemb, embb, nullptr, nullptr, EMBED, EMBED, b_em,
      Et, KPAD, 0, HIDDEN, INPUT, KPAD, EMBED, EMBED);

  // 4) fused split-K partials: which=0: xb @ Wgeb^T -> cols 0..1023
  //                            which=1: wb @ Et^T   -> cols 1024..2047
  gemm97<1, 1, 4><<<dim3(8, 4, 32), 256, 0, stream>>>(
      xb, Wgeb, wb, Et, KPAD, KPAD, nullptr,
      P, NOUT, BATCH * NOUT, BATCH, 1024, 1024, KPAD, 1280);

  // 5) reduce 16 planes -> combined bf16 [512, 2048] (+b_ge+lrelu on first half)
  reduce_kernel<16, 0><<<(BATCH * NOUT / 4) / 256, 256, 0, stream>>>(P, b_ge, comb);

  // 6) combiner partials: comb @ Wcb^T (M=512, N=2048, K=2048, S=4)
  gemm97<1, 0, 0><<<dim3(16, 4, 4), 256, 0, stream>>>(
      comb, Wcb, nullptr, nullptr, NOUT, NOUT, nullptr,
      P, NOUT, BATCH * NOUT, BATCH, NOUT, NOUT, NOUT, 512);

  // 7) reduce 4 planes + b_c + lrelu -> f32 out [512, 2048]
  reduce_kernel<4, 1><<<(BATCH * NOUT / 4) / 256, 256, 0, stream>>>(P, b_c, out);
}

// Round 3
// 248.180 us; speedup vs baseline: 1.4375x; 1.0330x over previous
//
#include <hip/hip_runtime.h>
#include <hip/hip_bf16.h>
#include <stdint.h>

#define BATCH  512
#define INPUT  20000
#define KPAD   20032     // INPUT padded to multiple of 64 (zero-filled tail)
#define NPADE  20224     // emb rows padded to multiple of 256 (zero-filled)
#define HIDDEN 1024
#define EMBED  512
#define NOUT   2048

typedef __attribute__((ext_vector_type(8))) __bf16 bf16x8;
typedef __attribute__((ext_vector_type(8))) unsigned short u16x8;
typedef __attribute__((ext_vector_type(4))) unsigned short u16x4;
typedef __attribute__((ext_vector_type(4))) float f32x4;

static __device__ __forceinline__ unsigned short f2bf(float f) {
  uint32_t u = __builtin_bit_cast(uint32_t, f);
  u += 0x7fffu + ((u >> 16) & 1u);          // round-to-nearest-even
  return (unsigned short)(u >> 16);
}

// async global->LDS, 16 bytes/lane; LDS dest is wave-uniform base (+lane*16 in HW)
static __device__ __forceinline__ void g2l16(const unsigned short* g, unsigned short* l) {
  __builtin_amdgcn_global_load_lds(
      (const __attribute__((address_space(1))) void*)g,
      (__attribute__((address_space(3))) void*)l, 16, 0, 0);
}

// f32 [rows,cols] -> bf16 [rowsPad,colsPad], zero-filled padding. cols % 8 == 0.
__global__ __launch_bounds__(256) void convert_kernel(
    const float* __restrict__ src, unsigned short* __restrict__ dst,
    int rows, int cols, int rowsPad, int colsPad)
{
  const int cpc = colsPad >> 3;             // chunks per row
  const int nchunks = rowsPad * cpc;
  for (int idx = blockIdx.x * 256 + threadIdx.x; idx < nchunks; idx += gridDim.x * 256) {
    int row = idx / cpc;
    int c0  = (idx - row * cpc) << 3;
    u16x8 v = {};
    if (row < rows && c0 < cols) {
      const float* p = src + (size_t)row * cols + c0;
      f32x4 f0 = *reinterpret_cast<const f32x4*>(p);
      f32x4 f1 = *reinterpret_cast<const f32x4*>(p + 4);
      v[0] = f2bf(f0[0]); v[1] = f2bf(f0[1]); v[2] = f2bf(f0[2]); v[3] = f2bf(f0[3]);
      v[4] = f2bf(f1[0]); v[5] = f2bf(f1[1]); v[6] = f2bf(f1[2]); v[7] = f2bf(f1[3]);
    }
    *reinterpret_cast<u16x8*>(dst + (size_t)row * colsPad + c0) = v;
  }
}

// ===== 256x256-tile, 8-wave, double-buffered 2-phase GEMM: C = A @ B^T =====
// A:[M,K] lda, B:[N,K] ldb, bf16, K-contiguous. BK=64. LDS 128 KiB (2 dbuf).
// Wave grid 2(M) x 4(N); per-wave output 128x64 = 8x4 fragments of 16x16.
// EPI 0: C[m,n] = bf16(lrelu(acc+bias[m])) for n<N, 0 for N<=n<Nw; skip n>=Nw.
// EPI 1: f32 split-K planes at Cp + z*pstride + m*ldc + which*1024 + n.
template<int EPI, int FUSED, int ZBITS>
__global__ __launch_bounds__(512, 2) void gemm256(
    const unsigned short* __restrict__ A0, const unsigned short* __restrict__ B0,
    const unsigned short* __restrict__ A1, const unsigned short* __restrict__ B1,
    int lda, int ldb,
    const float* __restrict__ bias,
    void* __restrict__ Cp, int ldc, int pstride,
    int M, int N, int Nw, int K, int kChunk)
{
  __shared__ __align__(16) unsigned short As[2][256 * 64];
  __shared__ __align__(16) unsigned short Bs[2][256 * 64];

  const int zall  = blockIdx.z;
  const int which = FUSED ? (zall >> ZBITS) : 0;
  const int z     = FUSED ? (zall & ((1 << ZBITS) - 1)) : zall;
  const unsigned short* A = (FUSED && which) ? A1 : A0;
  const unsigned short* B = (FUSED && which) ? B1 : B0;

  const int m0 = blockIdx.y * 256, n0 = blockIdx.x * 256;
  const int k0   = z * kChunk;
  const int kend = min(K, k0 + kChunk);
  const int nt   = (kend - k0) >> 6;

  const int tid = threadIdx.x;
  const int l = tid & 63, w = tid >> 6;

  // staging: round r stages rows [r*64, r*64+64); thread -> row r*64 + (tid>>3),
  // col (tid&7)*8. Wave w's lane block maps linearly to LDS base (r*64+w*8)*64.
  const int srow = tid >> 3;
  const int scol = (tid & 7) * 8;
  const unsigned short* ag = A + (size_t)(m0 + srow) * lda + scol;
  const unsigned short* bg = B + (size_t)(n0 + srow) * ldb + scol;

  const int wr = w >> 2, wc = w & 3;
  const int lr = l & 15, lk = (l >> 4) * 8;

  f32x4 acc[8][4] = {};

#define STAGE(buf, kb)                                                        \
  do {                                                                        \
    _Pragma("unroll")                                                         \
    for (int r = 0; r < 4; ++r)                                               \
      g2l16(ag + (size_t)(r * 64) * lda + (kb), &As[buf][(r * 64 + w * 8) * 64]); \
    _Pragma("unroll")                                                         \
    for (int r = 0; r < 4; ++r)                                               \
      g2l16(bg + (size_t)(r * 64) * ldb + (kb), &Bs[buf][(r * 64 + w * 8) * 64]); \
  } while (0)

  STAGE(0, k0);
  __syncthreads();

  int cur = 0;
  for (int t = 0; t < nt; ++t) {
    if (t + 1 < nt) {
      if (cur) STAGE(0, k0 + (t + 1) * 64);
      else     STAGE(1, k0 + (t + 1) * 64);
    }
#pragma unroll
    for (int ks = 0; ks < 2; ++ks) {
      bf16x8 a[8], b[4];
#pragma unroll
      for (int i = 0; i < 8; ++i)
        a[i] = *reinterpret_cast<const bf16x8*>(
            &As[cur][(wr * 128 + i * 16 + lr) * 64 + ks * 32 + lk]);
#pragma unroll
      for (int i = 0; i < 4; ++i)
        b[i] = *reinterpret_cast<const bf16x8*>(
            &Bs[cur][(wc * 64 + i * 16 + lr) * 64 + ks * 32 + lk]);
#pragma unroll
      for (int mi = 0; mi < 8; ++mi)
#pragma unroll
        for (int ni = 0; ni < 4; ++ni)
          acc[mi][ni] = __builtin_amdgcn_mfma_f32_16x16x32_bf16(a[mi], b[ni], acc[mi][ni], 0, 0, 0);
    }
    __syncthreads();   // vmcnt(0)+lgkmcnt(0)+barrier: next tile's loads landed
    cur ^= 1;
  }
#undef STAGE

  // C/D layout: col = lane&15, row = (lane>>4)*4 + reg  [m89/m91]
  const int rb = (l >> 4) * 4;
#pragma unroll
  for (int mi = 0; mi < 8; ++mi) {
#pragma unroll
    for (int ni = 0; ni < 4; ++ni) {
#pragma unroll
      for (int j = 0; j < 4; ++j) {
        int m = m0 + wr * 128 + mi * 16 + rb + j;
        int n = n0 + wc * 64 + ni * 16 + lr;
        float v = acc[mi][ni][j];
        if (EPI == 0) {
          if (n < Nw) {
            float t2 = v + bias[m];
            t2 = t2 > 0.f ? t2 : 0.01f * t2;
            reinterpret_cast<unsigned short*>(Cp)[(size_t)m * ldc + n] =
                (n < N) ? f2bf(t2) : (unsigned short)0;
          }
        } else {
          reinterpret_cast<float*>(Cp)[(size_t)z * pstride + (size_t)m * ldc +
                                       (FUSED ? which * 1024 : 0) + n] = v;
        }
      }
    }
  }
}

// ===== 128x128-tile m97-style GEMM (kept for the small combiner GEMM) =====
template<int EPI, int FUSED, int ZBITS>
__global__ __launch_bounds__(256) void gemm97(
    const unsigned short* __restrict__ A0, const unsigned short* __restrict__ B0,
    const unsigned short* __restrict__ A1, const unsigned short* __restrict__ B1,
    int lda, int ldb,
    const float* __restrict__ bias,
    void* __restrict__ Cp, int ldc, int pstride,
    int M, int N, int Nw, int K, int kChunk)
{
  __shared__ __align__(16) unsigned short As[128 * 64];
  __shared__ __align__(16) unsigned short Bs[128 * 64];

  const int zall  = blockIdx.z;
  const int which = FUSED ? (zall >> ZBITS) : 0;
  const int z     = FUSED ? (zall & ((1 << ZBITS) - 1)) : zall;
  const unsigned short* A = (FUSED && which) ? A1 : A0;
  const unsigned short* B = (FUSED && which) ? B1 : B0;

  const int m0 = blockIdx.y * 128, n0 = blockIdx.x * 128;
  const int k0   = z * kChunk;
  const int kend = min(K, k0 + kChunk);
  const int tid = threadIdx.x;
  const int l = tid & 63, w = tid >> 6;

  const int srow = w * 32 + (l >> 3);
  const int scol = (l & 7) * 8;
  const unsigned short* ag = A + (size_t)(m0 + srow) * lda + scol;
  const unsigned short* bg = B + (size_t)(n0 + srow) * ldb + scol;

  const int wm = (w >> 1) * 64, wn = (w & 1) * 64;
  const int lr = l & 15, lk = (l >> 4) * 8;

  f32x4 acc[4][4] = {};

  for (int kb = k0; kb < kend; kb += 64) {
#pragma unroll
    for (int j = 0; j < 4; ++j)
      g2l16(ag + (size_t)j * 8 * lda + kb, As + (w * 32 + j * 8) * 64);
#pragma unroll
    for (int j = 0; j < 4; ++j)
      g2l16(bg + (size_t)j * 8 * ldb + kb, Bs + (w * 32 + j * 8) * 64);
    __syncthreads();
#pragma unroll
    for (int ks = 0; ks < 2; ++ks) {
      bf16x8 a[4], b[4];
#pragma unroll
      for (int i = 0; i < 4; ++i)
        a[i] = *reinterpret_cast<const bf16x8*>(&As[(wm + i * 16 + lr) * 64 + ks * 32 + lk]);
#pragma unroll
      for (int i = 0; i < 4; ++i)
        b[i] = *reinterpret_cast<const bf16x8*>(&Bs[(wn + i * 16 + lr) * 64 + ks * 32 + lk]);
#pragma unroll
      for (int mi = 0; mi < 4; ++mi)
#pragma unroll
        for (int ni = 0; ni < 4; ++ni)
          acc[mi][ni] = __builtin_amdgcn_mfma_f32_16x16x32_bf16(a[mi], b[ni], acc[mi][ni], 0, 0, 0);
    }
    __syncthreads();
  }

  const int rb = (l >> 4) * 4;
#pragma unroll
  for (int mi = 0; mi < 4; ++mi) {
#pragma unroll
    for (int ni = 0; ni < 4; ++ni) {
#pragma unroll
      for (int j = 0; j < 4; ++j) {
        int m = m0 + wm + mi * 16 + rb + j;
        int n = n0 + wn + ni * 16 + lr;
        float v = acc[mi][ni][j];
        if (EPI == 0) {
          if (n < Nw) {
            float t = v + bias[m];
            t = t > 0.f ? t : 0.01f * t;
            reinterpret_cast<unsigned short*>(Cp)[(size_t)m * ldc + n] =
                (n < N) ? f2bf(t) : (unsigned short)0;
          }
        } else {
          reinterpret_cast<float*>(Cp)[(size_t)z * pstride + (size_t)m * ldc +
                                       (FUSED ? which * 1024 : 0) + n] = v;
        }
      }
    }
  }
}

// Per-row softmax stats + bf16 casts: xb = bf16(x), wb = bf16(softmax(x)),
// written at stride KPAD with zero-filled tail cols.
__global__ __launch_bounds__(256) void prep_x_kernel(
    const float* __restrict__ x,
    unsigned short* __restrict__ xb,
    unsigned short* __restrict__ wb)
{
  const int r = blockIdx.x;
  const int t = threadIdx.x;
  const float* xr = x + (size_t)r * INPUT;

  float m = -3.4e38f, s = 0.f;
  for (int c = t; c < INPUT / 4; c += 256) {
    float4 v = reinterpret_cast<const float4*>(xr)[c];
    float cm = fmaxf(fmaxf(v.x, v.y), fmaxf(v.z, v.w));
    if (cm > m) { s *= __expf(m - cm); m = cm; }
    s += __expf(v.x - m) + __expf(v.y - m) + __expf(v.z - m) + __expf(v.w - m);
  }
#pragma unroll
  for (int off = 32; off > 0; off >>= 1) {
    float om = __shfl_xor(m, off);
    float os = __shfl_xor(s, off);
    float nm = fmaxf(m, om);
    s = s * __expf(m - nm) + os * __expf(om - nm);
    m = nm;
  }
  __shared__ float sm[4], ss[4];
  if ((t & 63) == 0) { sm[t >> 6] = m; ss[t >> 6] = s; }
  __syncthreads();
  float M4 = fmaxf(fmaxf(sm[0], sm[1]), fmaxf(sm[2], sm[3]));
  float S4 = ss[0] * __expf(sm[0] - M4) + ss[1] * __expf(sm[1] - M4)
           + ss[2] * __expf(sm[2] - M4) + ss[3] * __expf(sm[3] - M4);
  float inv = 1.f / S4;

  unsigned short* xbr = xb + (size_t)r * KPAD;
  unsigned short* wbr = wb + (size_t)r * KPAD;
  for (int c = t; c < KPAD / 4; c += 256) {
    u16x4 xo = {}, wo = {};
    if (c < INPUT / 4) {
      float4 v = reinterpret_cast<const float4*>(xr)[c];
      xo[0] = f2bf(v.x); xo[1] = f2bf(v.y); xo[2] = f2bf(v.z); xo[3] = f2bf(v.w);
      wo[0] = f2bf(__expf(v.x - M4) * inv);
      wo[1] = f2bf(__expf(v.y - M4) * inv);
      wo[2] = f2bf(__expf(v.z - M4) * inv);
      wo[3] = f2bf(__expf(v.w - M4) * inv);
    }
    reinterpret_cast<u16x4*>(xbr)[c] = xo;
    reinterpret_cast<u16x4*>(wbr)[c] = wo;
  }
}

// Sum S split-K planes; MODE 0: combined buffer (b_ge+lrelu on cols<1024 only, bf16 out)
//                       MODE 1: final output (b_c+lrelu on all cols, f32 out)
template<int S, int MODE>
__global__ __launch_bounds__(256) void reduce_kernel(
    const float* __restrict__ P, const float* __restrict__ bias, void* __restrict__ outp)
{
  size_t base = ((size_t)blockIdx.x * 256 + threadIdx.x) * 4;
  f32x4 s = {};
#pragma unroll
  for (int zz = 0; zz < S; ++zz)
    s += *reinterpret_cast<const f32x4*>(P + (size_t)zz * BATCH * NOUT + base);
  int n = (int)(base & (NOUT - 1));
  if (MODE == 0) {
    u16x4 o;
    if (n < 1024) {
#pragma unroll
      for (int j = 0; j < 4; ++j) {
        float v = s[j] + bias[n + j];
        v = v > 0.f ? v : 0.01f * v;
        o[j] = f2bf(v);
      }
    } else {
#pragma unroll
      for (int j = 0; j < 4; ++j) o[j] = f2bf(s[j]);
    }
    *reinterpret_cast<u16x4*>(reinterpret_cast<unsigned short*>(outp) + base) = o;
  } else {
    f32x4 o;
#pragma unroll
    for (int j = 0; j < 4; ++j) {
      float v = s[j] + bias[n + j];
      o[j] = v > 0.f ? v : 0.01f * v;
    }
    *reinterpret_cast<f32x4*>(reinterpret_cast<float*>(outp) + base) = o;
  }
}

extern "C" void kernel_launch(void* const* d_in, const int* in_sizes, int n_in,
                              void* d_out, int out_size, void* d_ws, size_t ws_size,
                              hipStream_t stream)
{
  const float* x    = (const float*)d_in[0];
  const float* emb  = (const float*)d_in[1];
  const float* W_ge = (const float*)d_in[2];
  const float* b_ge = (const float*)d_in[3];
  const float* W_em = (const float*)d_in[4];
  const float* b_em = (const float*)d_in[5];
  const float* W_c  = (const float*)d_in[6];
  const float* b_c  = (const float*)d_in[7];
  float* out = (float*)d_out;

  char* ws = (char*)d_ws;
  // layout (bytes):
  unsigned short* xb   = (unsigned short*)(ws);                      // 512x20032 bf16  = 20,512,768
  unsigned short* wb   = (unsigned short*)(ws + 20512768);           // 20,512,768
  unsigned short* Wgeb = (unsigned short*)(ws + 41025536);           // 1024x20032 bf16 = 41,025,536
  unsigned short* Et   = (unsigned short*)(ws + 82051072);           // 1024x20032 bf16 = 41,025,536
  unsigned short* Wcb  = (unsigned short*)(ws + 123076608);          // 2048x2048 bf16  =  8,388,608
  unsigned short* comb = (unsigned short*)(ws + 131465216);          // 512x2048 bf16   =  2,097,152
  float*          P    = (float*)(ws + 133562368);                   // 16x512x2048 f32 = 67,108,864
  // embb/Wemb alias the P region (dead before P is first written)
  unsigned short* embb = (unsigned short*)(ws + 133562368);          // 20224x512 bf16  = 20,709,376
  unsigned short* Wemb = (unsigned short*)(ws + 133562368 + 20709376); // 1024x512 bf16 =  1,048,576
  // total ws usage: ~200.7 MB

  // 1) bf16 conversions (zero-padded)
  convert_kernel<<<1024, 256, 0, stream>>>(emb,  embb, INPUT, EMBED, NPADE, EMBED);
  convert_kernel<<<256,  256, 0, stream>>>(W_em, Wemb, HIDDEN, EMBED, HIDDEN, EMBED);
  convert_kernel<<<1024, 256, 0, stream>>>(W_ge, Wgeb, HIDDEN, INPUT, HIDDEN, KPAD);
  convert_kernel<<<512,  256, 0, stream>>>(W_c,  Wcb,  NOUT, NOUT, NOUT, NOUT);

  // 2) softmax stats + bf16 casts of x (stride KPAD, zero tail)
  prep_x_kernel<<<BATCH, 256, 0, stream>>>(x, xb, wb);

  // 3) Et[h,g] = lrelu(W_em @ emb^T + b_em): M=1024, N=20000 (Nw=20032), K=512
  gemm256<0, 0, 0><<<dim3(79, 4, 1), 512, 0, stream>>>(
      Wemb, embb, nullptr, nullptr, EMBED, EMBED, b_em,
      Et, KPAD, 0, HIDDEN, INPUT, KPAD, EMBED, EMBED);

  // 4) fused split-K partials: which=0: xb @ Wgeb^T -> cols 0..1023
  //                            which=1: wb @ Et^T   -> cols 1024..2047
  gemm256<1, 1, 4><<<dim3(4, 2, 32), 512, 0, stream>>>(
      xb, Wgeb, wb, Et, KPAD, KPAD, nullptr,
      P, NOUT, BATCH * NOUT, BATCH, 1024, 1024, KPAD, 1280);

  // 5) reduce 16 planes -> combined bf16 [512, 2048] (+b_ge+lrelu on first half)
  reduce_kernel<16, 0><<<(BATCH * NOUT / 4) / 256, 256, 0, stream>>>(P, b_ge, comb);

  // 6) combiner partials: comb @ Wcb^T (M=512, N=2048, K=2048, S=4)
  gemm97<1, 0, 0><<<dim3(16, 4, 4), 256, 0, stream>>>(
      comb, Wcb, nullptr, nullptr, NOUT, NOUT, nullptr,
      P, NOUT, BATCH * NOUT, BATCH, NOUT, NOUT, NOUT, 512);

  // 7) reduce 4 planes + b_c + lrelu -> f32 out [512, 2048]
  reduce_kernel<4, 1><<<(BATCH * NOUT / 4) / 256, 256, 0, stream>>>(P, b_c, out);
}

// Round 4
// 242.604 us; speedup vs baseline: 1.4706x; 1.0230x over previous
//
#include <hip/hip_runtime.h>
#include <hip/hip_bf16.h>
#include <stdint.h>

#define BATCH  512
#define INPUT  20000
#define KPAD   20032     // INPUT padded to multiple of 64 (zero-filled tail)
#define NPADE  20096     // emb rows padded to multiple of 128 (zero-filled)
#define HIDDEN 1024
#define EMBED  512
#define NOUT   2048

typedef __attribute__((ext_vector_type(8))) __bf16 bf16x8;
typedef __attribute__((ext_vector_type(8))) unsigned short u16x8;
typedef __attribute__((ext_vector_type(4))) unsigned short u16x4;
typedef __attribute__((ext_vector_type(4))) float f32x4;

static __device__ __forceinline__ unsigned short f2bf(float f) {
  uint32_t u = __builtin_bit_cast(uint32_t, f);
  u += 0x7fffu + ((u >> 16) & 1u);          // round-to-nearest-even
  return (unsigned short)(u >> 16);
}

// async global->LDS, 16 bytes/lane; LDS dest is wave-uniform base (+lane*16 in HW)
static __device__ __forceinline__ void g2l16(const unsigned short* g, unsigned short* l) {
  __builtin_amdgcn_global_load_lds(
      (const __attribute__((address_space(1))) void*)g,
      (__attribute__((address_space(3))) void*)l, 16, 0, 0);
}

#define MFMA(a, b, c) __builtin_amdgcn_mfma_f32_16x16x32_bf16((a), (b), (c), 0, 0, 0)

// ===================== 8-phase 256x256 fused split-K GEMM =====================
// which = blockIdx.z>>4 selects {xb,Wgeb} (cols 0..1023) vs {wb,Et} (cols 1024..2047).
// A:[512,KPAD], B:[1024,KPAD] bf16 K-contiguous. BK=64, 8 waves (2Mx4N), per-wave 128x64.
// Counted-vmcnt pipeline: boundary vmcnt(4) keeps 2 half-tiles in flight (never drain 0).
__global__ __launch_bounds__(512, 2) void gemm8p_fused(
    const unsigned short* __restrict__ xb, const unsigned short* __restrict__ Wgeb,
    const unsigned short* __restrict__ wb, const unsigned short* __restrict__ Etp,
    float* __restrict__ P, int kChunk)
{
  __shared__ __align__(16) unsigned short As[2][2][128 * 64];  // [buf][half]
  __shared__ __align__(16) unsigned short Bs[2][2][128 * 64];
  unsigned short* AsW = &As[0][0][0];
  unsigned short* BsW = &Bs[0][0][0];

  const int which = blockIdx.z >> 4;
  const int z     = blockIdx.z & 15;
  const unsigned short* Ap = which ? wb  : xb;
  const unsigned short* Bp = which ? Etp : Wgeb;

  const int m0 = blockIdx.y * 256, n0 = blockIdx.x * 256;
  const int k0   = z * kChunk;
  const int kend = min(KPAD, k0 + kChunk);
  const int nt   = (kend - k0) >> 6;

  const int tid = threadIdx.x;
  const int l = tid & 63, w = tid >> 6;
  const int srow = tid >> 3, scol = (tid & 7) * 8;

  const unsigned short* ag = Ap + (size_t)(m0 + srow) * KPAD + k0 + scol;
  const unsigned short* bg = Bp + (size_t)(n0 + srow) * KPAD + k0 + scol;

  const int wr = w >> 2, wc = w & 3;
  const int lr = l & 15, lk = (l >> 4) * 8;

  // stage half-tile h of A/B for K-offset dk (elements, rel. k0) into buffer buf
  auto stA = [&](int buf, int h, int dk) {
    const unsigned short* g = ag + (size_t)(h * 128) * KPAD + dk;
    unsigned short* d = AsW + (buf * 2 + h) * 8192 + (w * 8) * 64;
    g2l16(g, d);
    g2l16(g + (size_t)64 * KPAD, d + 64 * 64);
  };
  auto stB = [&](int buf, int h, int dk) {
    const unsigned short* g = bg + (size_t)(h * 128) * KPAD + dk;
    unsigned short* d = BsW + (buf * 2 + h) * 8192 + (w * 8) * 64;
    g2l16(g, d);
    g2l16(g + (size_t)64 * KPAD, d + 64 * 64);
  };
  // fragment reads (linear LDS)
  auto rdA = [&](int buf, int mi, int ks) -> bf16x8 {   // mi 0..7
    return *reinterpret_cast<const bf16x8*>(
        AsW + (buf * 2 + wr) * 8192 + (mi * 16 + lr) * 64 + ks * 32 + lk);
  };
  auto rdB = [&](int buf, int ni, int ks) -> bf16x8 {   // ni 0..3
    return *reinterpret_cast<const bf16x8*>(
        BsW + (buf * 2 + (wc >> 1)) * 8192 + ((wc & 1) * 64 + ni * 16 + lr) * 64 + ks * 32 + lk);
  };

  f32x4 acc[8][4] = {};

  // ---- prologue: tile0 fully + tile1 halves A0,B0 ----
  stA(0, 0, 0); stB(0, 0, 0); stA(0, 1, 0); stB(0, 1, 0);
  if (nt > 1) {
    stA(1, 0, 64); stB(1, 0, 64);
    asm volatile("s_waitcnt vmcnt(4)" ::: "memory");
  } else {
    asm volatile("s_waitcnt vmcnt(0)" ::: "memory");
  }
  __builtin_amdgcn_s_barrier();

  for (int t = 0; t < nt; ++t) {
    const int buf = t & 1, nb = buf ^ 1;
    const int dk1 = (t + 1) << 6, dk2 = (t + 2) << 6;
    bf16x8 a0[4][2], a1[4][2], b0[2][2], b1[2][2];

    // ---- phase 1: A-quarter0 x B-half0 ----
#pragma unroll
    for (int mi = 0; mi < 4; ++mi) { a0[mi][0] = rdA(buf, mi, 0); a0[mi][1] = rdA(buf, mi, 1); }
#pragma unroll
    for (int ni = 0; ni < 2; ++ni) { b0[ni][0] = rdB(buf, ni, 0); b0[ni][1] = rdB(buf, ni, 1); }
    if (t + 1 < nt) stA(nb, 1, dk1);
    __builtin_amdgcn_s_barrier();
    asm volatile("s_waitcnt lgkmcnt(0)" ::: "memory");
    __builtin_amdgcn_sched_barrier(0);
    __builtin_amdgcn_s_setprio(1);
#pragma unroll
    for (int mi = 0; mi < 4; ++mi)
#pragma unroll
      for (int ni = 0; ni < 2; ++ni) {
        acc[mi][ni] = MFMA(a0[mi][0], b0[ni][0], acc[mi][ni]);
        acc[mi][ni] = MFMA(a0[mi][1], b0[ni][1], acc[mi][ni]);
      }
    __builtin_amdgcn_s_setprio(0);
    __builtin_amdgcn_s_barrier();

    // ---- phase 2: A-quarter1 x B-half0 ----
#pragma unroll
    for (int mi = 0; mi < 4; ++mi) { a1[mi][0] = rdA(buf, mi + 4, 0); a1[mi][1] = rdA(buf, mi + 4, 1); }
    if (t + 1 < nt) stB(nb, 1, dk1);
    __builtin_amdgcn_s_barrier();
    asm volatile("s_waitcnt lgkmcnt(0)" ::: "memory");
    __builtin_amdgcn_sched_barrier(0);
    __builtin_amdgcn_s_setprio(1);
#pragma unroll
    for (int mi = 0; mi < 4; ++mi)
#pragma unroll
      for (int ni = 0; ni < 2; ++ni) {
        acc[mi + 4][ni] = MFMA(a1[mi][0], b0[ni][0], acc[mi + 4][ni]);
        acc[mi + 4][ni] = MFMA(a1[mi][1], b0[ni][1], acc[mi + 4][ni]);
      }
    __builtin_amdgcn_s_setprio(0);
    __builtin_amdgcn_s_barrier();

    // ---- phase 3: A-quarter1 x B-half1 (stage t+2.A0 into dead region of buf) ----
#pragma unroll
    for (int ni = 0; ni < 2; ++ni) { b1[ni][0] = rdB(buf, ni + 2, 0); b1[ni][1] = rdB(buf, ni + 2, 1); }
    if (t + 2 < nt) stA(buf, 0, dk2);
    __builtin_amdgcn_s_barrier();
    asm volatile("s_waitcnt lgkmcnt(0)" ::: "memory");
    __builtin_amdgcn_sched_barrier(0);
    __builtin_amdgcn_s_setprio(1);
#pragma unroll
    for (int mi = 0; mi < 4; ++mi)
#pragma unroll
      for (int ni = 0; ni < 2; ++ni) {
        acc[mi + 4][ni + 2] = MFMA(a1[mi][0], b1[ni][0], acc[mi + 4][ni + 2]);
        acc[mi + 4][ni + 2] = MFMA(a1[mi][1], b1[ni][1], acc[mi + 4][ni + 2]);
      }
    __builtin_amdgcn_s_setprio(0);
    __builtin_amdgcn_s_barrier();

    // ---- phase 4: A-quarter0 x B-half1 (stage t+2.B0; boundary vmcnt) ----
    if (t + 2 < nt) stB(buf, 0, dk2);
    __builtin_amdgcn_s_barrier();
    __builtin_amdgcn_sched_barrier(0);
    __builtin_amdgcn_s_setprio(1);
#pragma unroll
    for (int mi = 0; mi < 4; ++mi)
#pragma unroll
      for (int ni = 0; ni < 2; ++ni) {
        acc[mi][ni + 2] = MFMA(a0[mi][0], b1[ni][0], acc[mi][ni + 2]);
        acc[mi][ni + 2] = MFMA(a0[mi][1], b1[ni][1], acc[mi][ni + 2]);
      }
    __builtin_amdgcn_s_setprio(0);
    if (t + 2 < nt)      asm volatile("s_waitcnt vmcnt(4)" ::: "memory");
    else if (t + 1 < nt) asm volatile("s_waitcnt vmcnt(0)" ::: "memory");
    __builtin_amdgcn_s_barrier();
  }

  // C/D layout: col = lane&15, row = (lane>>4)*4 + reg  [m89/m91]
  const int rb = (l >> 4) * 4;
  float* dst = P + (size_t)z * (BATCH * NOUT) + which * 1024;
#pragma unroll
  for (int mi = 0; mi < 8; ++mi)
#pragma unroll
    for (int ni = 0; ni < 4; ++ni)
#pragma unroll
      for (int j = 0; j < 4; ++j) {
        int m = m0 + wr * 128 + mi * 16 + rb + j;
        int n = n0 + wc * 64 + ni * 16 + lr;
        dst[(size_t)m * NOUT + n] = acc[mi][ni][j];
      }
}

// ===== 128x128-tile m97-style GEMM (Et + combiner) =====
// EPI 0: C[m,n] = bf16(lrelu(acc+bias[m])) for n<N, 0 for N<=n<Nw; skip n>=Nw.
// EPI 1: f32 split-K planes at Cp + z*pstride + m*ldc + n.
template<int EPI>
__global__ __launch_bounds__(256) void gemm97(
    const unsigned short* __restrict__ A, const unsigned short* __restrict__ B,
    int lda, int ldb,
    const float* __restrict__ bias,
    void* __restrict__ Cp, int ldc, int pstride,
    int M, int N, int Nw, int K, int kChunk)
{
  __shared__ __align__(16) unsigned short As[128 * 64];
  __shared__ __align__(16) unsigned short Bs[128 * 64];

  const int z = blockIdx.z;
  const int m0 = blockIdx.y * 128, n0 = blockIdx.x * 128;
  const int k0   = z * kChunk;
  const int kend = min(K, k0 + kChunk);
  const int tid = threadIdx.x;
  const int l = tid & 63, w = tid >> 6;

  const int srow = w * 32 + (l >> 3);
  const int scol = (l & 7) * 8;
  const unsigned short* ag = A + (size_t)(m0 + srow) * lda + scol;
  const unsigned short* bg = B + (size_t)(n0 + srow) * ldb + scol;

  const int wm = (w >> 1) * 64, wn = (w & 1) * 64;
  const int lr = l & 15, lk = (l >> 4) * 8;

  f32x4 acc[4][4] = {};

  for (int kb = k0; kb < kend; kb += 64) {
#pragma unroll
    for (int j = 0; j < 4; ++j)
      g2l16(ag + (size_t)j * 8 * lda + kb, As + (w * 32 + j * 8) * 64);
#pragma unroll
    for (int j = 0; j < 4; ++j)
      g2l16(bg + (size_t)j * 8 * ldb + kb, Bs + (w * 32 + j * 8) * 64);
    __syncthreads();
#pragma unroll
    for (int ks = 0; ks < 2; ++ks) {
      bf16x8 a[4], b[4];
#pragma unroll
      for (int i = 0; i < 4; ++i)
        a[i] = *reinterpret_cast<const bf16x8*>(&As[(wm + i * 16 + lr) * 64 + ks * 32 + lk]);
#pragma unroll
      for (int i = 0; i < 4; ++i)
        b[i] = *reinterpret_cast<const bf16x8*>(&Bs[(wn + i * 16 + lr) * 64 + ks * 32 + lk]);
#pragma unroll
      for (int mi = 0; mi < 4; ++mi)
#pragma unroll
        for (int ni = 0; ni < 4; ++ni)
          acc[mi][ni] = MFMA(a[mi], b[ni], acc[mi][ni]);
    }
    __syncthreads();
  }

  const int rb = (l >> 4) * 4;
#pragma unroll
  for (int mi = 0; mi < 4; ++mi) {
#pragma unroll
    for (int ni = 0; ni < 4; ++ni) {
#pragma unroll
      for (int j = 0; j < 4; ++j) {
        int m = m0 + wm + mi * 16 + rb + j;
        int n = n0 + wn + ni * 16 + lr;
        float v = acc[mi][ni][j];
        if (EPI == 0) {
          if (n < Nw) {
            float t = v + bias[m];
            t = t > 0.f ? t : 0.01f * t;
            reinterpret_cast<unsigned short*>(Cp)[(size_t)m * ldc + n] =
                (n < N) ? f2bf(t) : (unsigned short)0;
          }
        } else {
          reinterpret_cast<float*>(Cp)[(size_t)z * pstride + (size_t)m * ldc + n] = v;
        }
      }
    }
  }
}

// f32 [rows,cols] -> bf16 [rowsPad,colsPad], zero-filled padding. cols % 8 == 0.
__global__ __launch_bounds__(256) void convert_kernel(
    const float* __restrict__ src, unsigned short* __restrict__ dst,
    int rows, int cols, int rowsPad, int colsPad)
{
  const int cpc = colsPad >> 3;
  const int nchunks = rowsPad * cpc;
  for (int idx = blockIdx.x * 256 + threadIdx.x; idx < nchunks; idx += gridDim.x * 256) {
    int row = idx / cpc;
    int c0  = (idx - row * cpc) << 3;
    u16x8 v = {};
    if (row < rows && c0 < cols) {
      const float* p = src + (size_t)row * cols + c0;
      f32x4 f0 = *reinterpret_cast<const f32x4*>(p);
      f32x4 f1 = *reinterpret_cast<const f32x4*>(p + 4);
      v[0] = f2bf(f0[0]); v[1] = f2bf(f0[1]); v[2] = f2bf(f0[2]); v[3] = f2bf(f0[3]);
      v[4] = f2bf(f1[0]); v[5] = f2bf(f1[1]); v[6] = f2bf(f1[2]); v[7] = f2bf(f1[3]);
    }
    *reinterpret_cast<u16x8*>(dst + (size_t)row * colsPad + c0) = v;
  }
}

// Per-row softmax stats + bf16 casts: xb = bf16(x), wb = bf16(softmax(x)), stride KPAD.
__global__ __launch_bounds__(256) void prep_x_kernel(
    const float* __restrict__ x,
    unsigned short* __restrict__ xb,
    unsigned short* __restrict__ wb)
{
  const int r = blockIdx.x;
  const int t = threadIdx.x;
  const float* xr = x + (size_t)r * INPUT;

  float m = -3.4e38f, s = 0.f;
  for (int c = t; c < INPUT / 4; c += 256) {
    float4 v = reinterpret_cast<const float4*>(xr)[c];
    float cm = fmaxf(fmaxf(v.x, v.y), fmaxf(v.z, v.w));
    if (cm > m) { s *= __expf(m - cm); m = cm; }
    s += __expf(v.x - m) + __expf(v.y - m) + __expf(v.z - m) + __expf(v.w - m);
  }
#pragma unroll
  for (int off = 32; off > 0; off >>= 1) {
    float om = __shfl_xor(m, off);
    float os = __shfl_xor(s, off);
    float nm = fmaxf(m, om);
    s = s * __expf(m - nm) + os * __expf(om - nm);
    m = nm;
  }
  __shared__ float sm[4], ss[4];
  if ((t & 63) == 0) { sm[t >> 6] = m; ss[t >> 6] = s; }
  __syncthreads();
  float M4 = fmaxf(fmaxf(sm[0], sm[1]), fmaxf(sm[2], sm[3]));
  float S4 = ss[0] * __expf(sm[0] - M4) + ss[1] * __expf(sm[1] - M4)
           + ss[2] * __expf(sm[2] - M4) + ss[3] * __expf(sm[3] - M4);
  float inv = 1.f / S4;

  unsigned short* xbr = xb + (size_t)r * KPAD;
  unsigned short* wbr = wb + (size_t)r * KPAD;
  for (int c = t; c < KPAD / 4; c += 256) {
    u16x4 xo = {}, wo = {};
    if (c < INPUT / 4) {
      float4 v = reinterpret_cast<const float4*>(xr)[c];
      xo[0] = f2bf(v.x); xo[1] = f2bf(v.y); xo[2] = f2bf(v.z); xo[3] = f2bf(v.w);
      wo[0] = f2bf(__expf(v.x - M4) * inv);
      wo[1] = f2bf(__expf(v.y - M4) * inv);
      wo[2] = f2bf(__expf(v.z - M4) * inv);
      wo[3] = f2bf(__expf(v.w - M4) * inv);
    }
    reinterpret_cast<u16x4*>(xbr)[c] = xo;
    reinterpret_cast<u16x4*>(wbr)[c] = wo;
  }
}

// Sum S split-K planes; MODE 0: combined buffer (b_ge+lrelu on cols<1024 only, bf16 out)
//                       MODE 1: final output (b_c+lrelu on all cols, f32 out)
template<int S, int MODE>
__global__ __launch_bounds__(256) void reduce_kernel(
    const float* __restrict__ P, const float* __restrict__ bias, void* __restrict__ outp)
{
  size_t base = ((size_t)blockIdx.x * 256 + threadIdx.x) * 4;
  f32x4 s = {};
#pragma unroll
  for (int zz = 0; zz < S; ++zz)
    s += *reinterpret_cast<const f32x4*>(P + (size_t)zz * BATCH * NOUT + base);
  int n = (int)(base & (NOUT - 1));
  if (MODE == 0) {
    u16x4 o;
    if (n < 1024) {
#pragma unroll
      for (int j = 0; j < 4; ++j) {
        float v = s[j] + bias[n + j];
        v = v > 0.f ? v : 0.01f * v;
        o[j] = f2bf(v);
      }
    } else {
#pragma unroll
      for (int j = 0; j < 4; ++j) o[j] = f2bf(s[j]);
    }
    *reinterpret_cast<u16x4*>(reinterpret_cast<unsigned short*>(outp) + base) = o;
  } else {
    f32x4 o;
#pragma unroll
    for (int j = 0; j < 4; ++j) {
      float v = s[j] + bias[n + j];
      o[j] = v > 0.f ? v : 0.01f * v;
    }
    *reinterpret_cast<f32x4*>(reinterpret_cast<float*>(outp) + base) = o;
  }
}

extern "C" void kernel_launch(void* const* d_in, const int* in_sizes, int n_in,
                              void* d_out, int out_size, void* d_ws, size_t ws_size,
                              hipStream_t stream)
{
  const float* x    = (const float*)d_in[0];
  const float* emb  = (const float*)d_in[1];
  const float* W_ge = (const float*)d_in[2];
  const float* b_ge = (const float*)d_in[3];
  const float* W_em = (const float*)d_in[4];
  const float* b_em = (const float*)d_in[5];
  const float* W_c  = (const float*)d_in[6];
  const float* b_c  = (const float*)d_in[7];
  float* out = (float*)d_out;

  char* ws = (char*)d_ws;
  unsigned short* xb   = (unsigned short*)(ws);                      // 512x20032 bf16  = 20,512,768
  unsigned short* wb   = (unsigned short*)(ws + 20512768);           // 20,512,768
  unsigned short* Wgeb = (unsigned short*)(ws + 41025536);           // 1024x20032 bf16 = 41,025,536
  unsigned short* Et   = (unsigned short*)(ws + 82051072);           // 1024x20032 bf16 = 41,025,536
  unsigned short* Wcb  = (unsigned short*)(ws + 123076608);          // 2048x2048 bf16  =  8,388,608
  unsigned short* comb = (unsigned short*)(ws + 131465216);          // 512x2048 bf16   =  2,097,152
  float*          P    = (float*)(ws + 133562368);                   // 16x512x2048 f32 = 67,108,864
  // embb/Wemb alias the P region (dead before P is first written)
  unsigned short* embb = (unsigned short*)(ws + 133562368);          // 20096x512 bf16  = 20,578,304
  unsigned short* Wemb = (unsigned short*)(ws + 133562368 + 20578304); // 1024x512 bf16 =  1,048,576
  // total ws usage: ~200.7 MB

  // 1) bf16 conversions (zero-padded)
  convert_kernel<<<1024, 256, 0, stream>>>(emb,  embb, INPUT, EMBED, NPADE, EMBED);
  convert_kernel<<<256,  256, 0, stream>>>(W_em, Wemb, HIDDEN, EMBED, HIDDEN, EMBED);
  convert_kernel<<<1024, 256, 0, stream>>>(W_ge, Wgeb, HIDDEN, INPUT, HIDDEN, KPAD);
  convert_kernel<<<512,  256, 0, stream>>>(W_c,  Wcb,  NOUT, NOUT, NOUT, NOUT);

  // 2) softmax stats + bf16 casts of x (stride KPAD, zero tail)
  prep_x_kernel<<<BATCH, 256, 0, stream>>>(x, xb, wb);

  // 3) Et[h,g] = lrelu(W_em @ emb^T + b_em): M=1024, N=20000 (Nw=20032), K=512
  gemm97<0><<<dim3(157, 8, 1), 256, 0, stream>>>(
      Wemb, embb, EMBED, EMBED, b_em,
      Et, KPAD, 0, HIDDEN, INPUT, KPAD, EMBED, EMBED);

  // 4) fused split-K partials (8-phase counted-vmcnt pipeline):
  //    which=0: xb @ Wgeb^T -> cols 0..1023 ; which=1: wb @ Et^T -> cols 1024..2047
  gemm8p_fused<<<dim3(4, 2, 32), 512, 0, stream>>>(xb, Wgeb, wb, Et, P, 1280);

  // 5) reduce 16 planes -> combined bf16 [512, 2048] (+b_ge+lrelu on first half)
  reduce_kernel<16, 0><<<(BATCH * NOUT / 4) / 256, 256, 0, stream>>>(P, b_ge, comb);

  // 6) combiner partials: comb @ Wcb^T (M=512, N=2048, K=2048, S=4)
  gemm97<1><<<dim3(16, 4, 4), 256, 0, stream>>>(
      comb, Wcb, NOUT, NOUT, nullptr,
      P, NOUT, BATCH * NOUT, BATCH, NOUT, NOUT, NOUT, 512);

  // 7) reduce 4 planes + b_c + lrelu -> f32 out [512, 2048]
  reduce_kernel<4, 1><<<(BATCH * NOUT / 4) / 256, 256, 0, stream>>>(P, b_c, out);
}